// Round 3
// baseline (1574.702 us; speedup 1.0000x reference)
//
#include <hip/hip_runtime.h>

#define NUM_USERS 100000
#define NUM_ITEMS 50000
#define NUM_EDGES 4000000
#define DIM 64

// ---------------- fallback: scatter-atomic (round-1 kernel) ----------------
__global__ __launch_bounds__(256) void lightgcn_scatter(
    const float* __restrict__ user_emb,
    const float* __restrict__ item_emb,
    const float* __restrict__ edge_norm,
    const int* __restrict__ u_idx,
    const int* __restrict__ i_idx,
    float* __restrict__ agg_users,
    float* __restrict__ agg_items)
{
    long long gid = (long long)blockIdx.x * blockDim.x + threadIdx.x;
    int edge = (int)(gid >> 6);
    int lane = (int)(gid & 63);
    if (edge >= NUM_EDGES) return;
    int u = u_idx[edge];
    int i = i_idx[edge];
    float n = edge_norm[edge];
    float uval = user_emb[(size_t)u * DIM + lane];
    float ival = item_emb[(size_t)i * DIM + lane];
    atomicAdd(&agg_items[(size_t)i * DIM + lane], n * uval);
    atomicAdd(&agg_users[(size_t)u * DIM + lane], n * ival);
}

// ---------------- CSR build ----------------
// 4 edges per thread via int4 loads.
__global__ __launch_bounds__(256) void edge_hist(
    const int4* __restrict__ u4, const int4* __restrict__ i4,
    int* __restrict__ u_cnt, int* __restrict__ i_cnt)
{
    int t = blockIdx.x * blockDim.x + threadIdx.x;
    if (t >= NUM_EDGES / 4) return;
    int4 u = u4[t];
    int4 i = i4[t];
    atomicAdd(&i_cnt[i.x], 1);
    atomicAdd(&i_cnt[i.y], 1);
    atomicAdd(&i_cnt[i.z], 1);
    atomicAdd(&i_cnt[i.w], 1);
    atomicAdd(&u_cnt[u.x], 1);
    atomicAdd(&u_cnt[u.y], 1);
    atomicAdd(&u_cnt[u.z], 1);
    atomicAdd(&u_cnt[u.w], 1);
}

// grid=2: block 0 scans item counts (n=NUM_ITEMS), block 1 scans user counts.
// In-place: cnt[] becomes exclusive offsets, cnt[n] = total, cur[] = offsets copy.
__global__ __launch_bounds__(1024) void scan_offsets(
    int* __restrict__ i_off, int* __restrict__ i_cur,
    int* __restrict__ u_off, int* __restrict__ u_cur)
{
    int* cnt; int* cur; int n;
    if (blockIdx.x == 0) { cnt = i_off; cur = i_cur; n = NUM_ITEMS; }
    else                 { cnt = u_off; cur = u_cur; n = NUM_USERS; }
    const int t = threadIdx.x;
    const int chunk = (n + 1023) / 1024;
    const int base = t * chunk;
    const int lim  = (base + chunk < n) ? base + chunk : n;

    int local = 0;
    for (int i = base; i < lim; ++i) local += cnt[i];

    __shared__ int s[1024];
    s[t] = local;
    __syncthreads();
    for (int off = 1; off < 1024; off <<= 1) {
        int v = (t >= off) ? s[t - off] : 0;
        __syncthreads();
        s[t] += v;
        __syncthreads();
    }
    int running = (t == 0) ? 0 : s[t - 1];
    if (t == 1023) cnt[n] = s[1023];
    for (int i = base; i < lim; ++i) {
        int c = cnt[i];
        cnt[i] = running;
        cur[i] = running;
        running += c;
    }
}

// Packed placement: one aligned 8B int2 store per edge per direction.
__global__ __launch_bounds__(256) void edge_place(
    const int* __restrict__ u_idx, const int* __restrict__ i_idx,
    const float* __restrict__ edge_norm,
    int* __restrict__ i_cur, int* __restrict__ u_cur,
    int2* __restrict__ ci, int2* __restrict__ cu)
{
    int e = blockIdx.x * blockDim.x + threadIdx.x;
    if (e >= NUM_EDGES) return;
    int u = u_idx[e];
    int i = i_idx[e];
    int wbits = __float_as_int(edge_norm[e]);
    int pi = atomicAdd(&i_cur[i], 1);
    ci[pi] = make_int2(u, wbits);
    int pu = atomicAdd(&u_cur[u], 1);
    cu[pu] = make_int2(i, wbits);
}

// ---------------- gather: one 64-lane wave per output row ----------------
__global__ __launch_bounds__(256) void gather_rows(
    const int* __restrict__ off, const int2* __restrict__ edges,
    const float* __restrict__ emb,
    float* __restrict__ out, int nrows)
{
    int gid  = blockIdx.x * blockDim.x + threadIdx.x;
    int row  = gid >> 6;
    int lane = gid & 63;
    if (row >= nrows) return;
    int s = off[row];
    int e = off[row + 1];
    float acc = 0.f;
    int k = s;
    for (; k + 8 <= e; k += 8) {
        int2 e0 = edges[k],   e1 = edges[k+1], e2 = edges[k+2], e3 = edges[k+3];
        int2 e4 = edges[k+4], e5 = edges[k+5], e6 = edges[k+6], e7 = edges[k+7];
        float v0 = emb[(size_t)e0.x * DIM + lane];
        float v1 = emb[(size_t)e1.x * DIM + lane];
        float v2 = emb[(size_t)e2.x * DIM + lane];
        float v3 = emb[(size_t)e3.x * DIM + lane];
        float v4 = emb[(size_t)e4.x * DIM + lane];
        float v5 = emb[(size_t)e5.x * DIM + lane];
        float v6 = emb[(size_t)e6.x * DIM + lane];
        float v7 = emb[(size_t)e7.x * DIM + lane];
        acc += __int_as_float(e0.y) * v0;
        acc += __int_as_float(e1.y) * v1;
        acc += __int_as_float(e2.y) * v2;
        acc += __int_as_float(e3.y) * v3;
        acc += __int_as_float(e4.y) * v4;
        acc += __int_as_float(e5.y) * v5;
        acc += __int_as_float(e6.y) * v6;
        acc += __int_as_float(e7.y) * v7;
    }
    for (; k < e; ++k) {
        int2 t = edges[k];
        acc += __int_as_float(t.y) * emb[(size_t)t.x * DIM + lane];
    }
    out[(size_t)row * DIM + lane] = acc;
}

extern "C" void kernel_launch(void* const* d_in, const int* in_sizes, int n_in,
                              void* d_out, int out_size, void* d_ws, size_t ws_size,
                              hipStream_t stream) {
    const float* user_emb  = (const float*)d_in[0];
    const float* item_emb  = (const float*)d_in[1];
    const float* edge_norm = (const float*)d_in[2];
    const int*   u_idx     = (const int*)d_in[3];
    const int*   i_idx     = (const int*)d_in[4];

    float* agg_users = (float*)d_out;                        // 100000*64
    float* agg_items = agg_users + (size_t)NUM_USERS * DIM;  // 50000*64

    const size_t need = ((size_t)(NUM_ITEMS + 1) + (NUM_USERS + 1)
                       + NUM_ITEMS + NUM_USERS) * sizeof(int)
                      + (size_t)NUM_EDGES * 2 * sizeof(int2);

    if (ws_size < need) {
        hipMemsetAsync(d_out, 0, (size_t)out_size * sizeof(float), stream);
        const long long total_threads = (long long)NUM_EDGES * 64;
        const int blocks = (int)((total_threads + 255) / 256);
        lightgcn_scatter<<<blocks, 256, 0, stream>>>(
            user_emb, item_emb, edge_norm, u_idx, i_idx, agg_users, agg_items);
        return;
    }

    char* p = (char*)d_ws;
    int*  i_off = (int*)p;  p += (size_t)(NUM_ITEMS + 1) * sizeof(int);
    int*  u_off = (int*)p;  p += (size_t)(NUM_USERS + 1) * sizeof(int);
    int*  i_cur = (int*)p;  p += (size_t)NUM_ITEMS * sizeof(int);
    int*  u_cur = (int*)p;  p += (size_t)NUM_USERS * sizeof(int);
    // 8B-align for int2
    p = (char*)(((uintptr_t)p + 15) & ~(uintptr_t)15);
    int2* ci = (int2*)p;    p += (size_t)NUM_EDGES * sizeof(int2);
    int2* cu = (int2*)p;    p += (size_t)NUM_EDGES * sizeof(int2);

    // zero count arrays (i_off and u_off are contiguous); output NOT zeroed
    // (gather writes every element).
    hipMemsetAsync(i_off, 0, (size_t)(NUM_ITEMS + 1 + NUM_USERS + 1) * sizeof(int),
                   stream);

    edge_hist<<<(NUM_EDGES / 4 + 255) / 256, 256, 0, stream>>>(
        (const int4*)u_idx, (const int4*)i_idx, u_off, i_off);
    scan_offsets<<<2, 1024, 0, stream>>>(i_off, i_cur, u_off, u_cur);
    edge_place<<<(NUM_EDGES + 255) / 256, 256, 0, stream>>>(
        u_idx, i_idx, edge_norm, i_cur, u_cur, ci, cu);

    // agg_items[i] = sum over edges of norm * user_emb[u]
    gather_rows<<<((NUM_ITEMS * 64) + 255) / 256, 256, 0, stream>>>(
        i_off, ci, user_emb, agg_items, NUM_ITEMS);
    // agg_users[u] = sum over edges of norm * item_emb[i]
    gather_rows<<<((NUM_USERS * 64) + 255) / 256, 256, 0, stream>>>(
        u_off, cu, item_emb, agg_users, NUM_USERS);
}

// Round 4
// 1272.454 us; speedup vs baseline: 1.2375x; 1.2375x over previous
//
#include <hip/hip_runtime.h>
#include <hip/hip_bf16.h>

#define NUM_USERS 100000
#define NUM_ITEMS 50000
#define NUM_EDGES 4000000
#define DIM 64

// ---------------- fallback: scatter-atomic (round-1 kernel) ----------------
__global__ __launch_bounds__(256) void lightgcn_scatter(
    const float* __restrict__ user_emb,
    const float* __restrict__ item_emb,
    const float* __restrict__ edge_norm,
    const int* __restrict__ u_idx,
    const int* __restrict__ i_idx,
    float* __restrict__ agg_users,
    float* __restrict__ agg_items)
{
    long long gid = (long long)blockIdx.x * blockDim.x + threadIdx.x;
    int edge = (int)(gid >> 6);
    int lane = (int)(gid & 63);
    if (edge >= NUM_EDGES) return;
    int u = u_idx[edge];
    int i = i_idx[edge];
    float n = edge_norm[edge];
    float uval = user_emb[(size_t)u * DIM + lane];
    float ival = item_emb[(size_t)i * DIM + lane];
    atomicAdd(&agg_items[(size_t)i * DIM + lane], n * uval);
    atomicAdd(&agg_users[(size_t)u * DIM + lane], n * ival);
}

// ---------------- bf16 conversion of embedding tables ----------------
// 4 floats -> 4 bf16 (RNE) per thread.
__global__ __launch_bounds__(256) void convert_bf16(
    const float4* __restrict__ src, ushort* __restrict__ dst, int n4)
{
    int t = blockIdx.x * blockDim.x + threadIdx.x;
    if (t >= n4) return;
    float4 v = src[t];
    ushort4 o;
    uint b;
    b = __float_as_uint(v.x); o.x = (ushort)((b + 0x7FFFu + ((b >> 16) & 1u)) >> 16);
    b = __float_as_uint(v.y); o.y = (ushort)((b + 0x7FFFu + ((b >> 16) & 1u)) >> 16);
    b = __float_as_uint(v.z); o.z = (ushort)((b + 0x7FFFu + ((b >> 16) & 1u)) >> 16);
    b = __float_as_uint(v.w); o.w = (ushort)((b + 0x7FFFu + ((b >> 16) & 1u)) >> 16);
    ((ushort4*)dst)[t] = o;
}

// ---------------- CSR build ----------------
// 4 edges per thread via int4 loads.
__global__ __launch_bounds__(256) void edge_hist(
    const int4* __restrict__ u4, const int4* __restrict__ i4,
    int* __restrict__ u_cnt, int* __restrict__ i_cnt)
{
    int t = blockIdx.x * blockDim.x + threadIdx.x;
    if (t >= NUM_EDGES / 4) return;
    int4 u = u4[t];
    int4 i = i4[t];
    atomicAdd(&i_cnt[i.x], 1);
    atomicAdd(&i_cnt[i.y], 1);
    atomicAdd(&i_cnt[i.z], 1);
    atomicAdd(&i_cnt[i.w], 1);
    atomicAdd(&u_cnt[u.x], 1);
    atomicAdd(&u_cnt[u.y], 1);
    atomicAdd(&u_cnt[u.z], 1);
    atomicAdd(&u_cnt[u.w], 1);
}

// grid=2: block 0 scans item counts, block 1 scans user counts.
__global__ __launch_bounds__(1024) void scan_offsets(
    int* __restrict__ i_off, int* __restrict__ i_cur,
    int* __restrict__ u_off, int* __restrict__ u_cur)
{
    int* cnt; int* cur; int n;
    if (blockIdx.x == 0) { cnt = i_off; cur = i_cur; n = NUM_ITEMS; }
    else                 { cnt = u_off; cur = u_cur; n = NUM_USERS; }
    const int t = threadIdx.x;
    const int chunk = (n + 1023) / 1024;
    const int base = t * chunk;
    const int lim  = (base + chunk < n) ? base + chunk : n;

    int local = 0;
    for (int i = base; i < lim; ++i) local += cnt[i];

    __shared__ int s[1024];
    s[t] = local;
    __syncthreads();
    for (int off = 1; off < 1024; off <<= 1) {
        int v = (t >= off) ? s[t - off] : 0;
        __syncthreads();
        s[t] += v;
        __syncthreads();
    }
    int running = (t == 0) ? 0 : s[t - 1];
    if (t == 1023) cnt[n] = s[1023];
    for (int i = base; i < lim; ++i) {
        int c = cnt[i];
        cnt[i] = running;
        cur[i] = running;
        running += c;
    }
}

// Placement: 4 separate 4B scattered stores per edge (empirically ~2x faster
// than packed int2 8B stores on gfx950 — round-3 regression evidence).
__global__ __launch_bounds__(256) void edge_place(
    const int* __restrict__ u_idx, const int* __restrict__ i_idx,
    const float* __restrict__ edge_norm,
    int* __restrict__ i_cur, int* __restrict__ u_cur,
    int* __restrict__ ci_src, float* __restrict__ ci_w,
    int* __restrict__ cu_src, float* __restrict__ cu_w)
{
    int e = blockIdx.x * blockDim.x + threadIdx.x;
    if (e >= NUM_EDGES) return;
    int u = u_idx[e];
    int i = i_idx[e];
    float w = edge_norm[e];
    int pi = atomicAdd(&i_cur[i], 1);
    ci_src[pi] = u;  ci_w[pi] = w;
    int pu = atomicAdd(&u_cur[u], 1);
    cu_src[pu] = i;  cu_w[pu] = w;
}

// ---------------- gather (bf16 table): one 64-lane wave per output row ------
__global__ __launch_bounds__(256) void gather_rows_bf16(
    const int* __restrict__ off, const int* __restrict__ src,
    const float* __restrict__ w, const ushort* __restrict__ emb16,
    float* __restrict__ out, int nrows)
{
    int gid  = blockIdx.x * blockDim.x + threadIdx.x;
    int row  = gid >> 6;
    int lane = gid & 63;
    if (row >= nrows) return;
    int s = off[row];
    int e = off[row + 1];
    float acc = 0.f;
    int k = s;
    for (; k + 8 <= e; k += 8) {
        int   s0 = src[k],   s1 = src[k+1], s2 = src[k+2], s3 = src[k+3];
        int   s4 = src[k+4], s5 = src[k+5], s6 = src[k+6], s7 = src[k+7];
        float w0 = w[k],   w1 = w[k+1], w2 = w[k+2], w3 = w[k+3];
        float w4 = w[k+4], w5 = w[k+5], w6 = w[k+6], w7 = w[k+7];
        ushort b0 = emb16[(size_t)s0 * DIM + lane];
        ushort b1 = emb16[(size_t)s1 * DIM + lane];
        ushort b2 = emb16[(size_t)s2 * DIM + lane];
        ushort b3 = emb16[(size_t)s3 * DIM + lane];
        ushort b4 = emb16[(size_t)s4 * DIM + lane];
        ushort b5 = emb16[(size_t)s5 * DIM + lane];
        ushort b6 = emb16[(size_t)s6 * DIM + lane];
        ushort b7 = emb16[(size_t)s7 * DIM + lane];
        acc += w0 * __uint_as_float((uint)b0 << 16);
        acc += w1 * __uint_as_float((uint)b1 << 16);
        acc += w2 * __uint_as_float((uint)b2 << 16);
        acc += w3 * __uint_as_float((uint)b3 << 16);
        acc += w4 * __uint_as_float((uint)b4 << 16);
        acc += w5 * __uint_as_float((uint)b5 << 16);
        acc += w6 * __uint_as_float((uint)b6 << 16);
        acc += w7 * __uint_as_float((uint)b7 << 16);
    }
    for (; k < e; ++k) {
        ushort b = emb16[(size_t)src[k] * DIM + lane];
        acc += w[k] * __uint_as_float((uint)b << 16);
    }
    out[(size_t)row * DIM + lane] = acc;
}

// ---------------- gather (fp32 table) — mid-tier fallback ----------------
__global__ __launch_bounds__(256) void gather_rows_f32(
    const int* __restrict__ off, const int* __restrict__ src,
    const float* __restrict__ w, const float* __restrict__ emb,
    float* __restrict__ out, int nrows)
{
    int gid  = blockIdx.x * blockDim.x + threadIdx.x;
    int row  = gid >> 6;
    int lane = gid & 63;
    if (row >= nrows) return;
    int s = off[row];
    int e = off[row + 1];
    float acc = 0.f;
    int k = s;
    for (; k + 8 <= e; k += 8) {
        int   s0 = src[k],   s1 = src[k+1], s2 = src[k+2], s3 = src[k+3];
        int   s4 = src[k+4], s5 = src[k+5], s6 = src[k+6], s7 = src[k+7];
        float w0 = w[k],   w1 = w[k+1], w2 = w[k+2], w3 = w[k+3];
        float w4 = w[k+4], w5 = w[k+5], w6 = w[k+6], w7 = w[k+7];
        acc += w0 * emb[(size_t)s0 * DIM + lane];
        acc += w1 * emb[(size_t)s1 * DIM + lane];
        acc += w2 * emb[(size_t)s2 * DIM + lane];
        acc += w3 * emb[(size_t)s3 * DIM + lane];
        acc += w4 * emb[(size_t)s4 * DIM + lane];
        acc += w5 * emb[(size_t)s5 * DIM + lane];
        acc += w6 * emb[(size_t)s6 * DIM + lane];
        acc += w7 * emb[(size_t)s7 * DIM + lane];
    }
    for (; k < e; ++k) acc += w[k] * emb[(size_t)src[k] * DIM + lane];
    out[(size_t)row * DIM + lane] = acc;
}

extern "C" void kernel_launch(void* const* d_in, const int* in_sizes, int n_in,
                              void* d_out, int out_size, void* d_ws, size_t ws_size,
                              hipStream_t stream) {
    const float* user_emb  = (const float*)d_in[0];
    const float* item_emb  = (const float*)d_in[1];
    const float* edge_norm = (const float*)d_in[2];
    const int*   u_idx     = (const int*)d_in[3];
    const int*   i_idx     = (const int*)d_in[4];

    float* agg_users = (float*)d_out;                        // 100000*64
    float* agg_items = agg_users + (size_t)NUM_USERS * DIM;  // 50000*64

    const size_t off_bytes = ((size_t)(NUM_ITEMS + 1) + (NUM_USERS + 1)
                            + NUM_ITEMS + NUM_USERS) * sizeof(int);
    const size_t csr_bytes = (size_t)NUM_EDGES * 2 * (sizeof(int) + sizeof(float));
    const size_t bf16_bytes = ((size_t)NUM_USERS + NUM_ITEMS) * DIM * sizeof(ushort);
    const size_t need_csr  = off_bytes + 64 + csr_bytes;
    const size_t need_full = need_csr + 64 + bf16_bytes;

    if (ws_size < need_csr) {
        // lowest tier: scatter-atomic
        hipMemsetAsync(d_out, 0, (size_t)out_size * sizeof(float), stream);
        const long long total_threads = (long long)NUM_EDGES * 64;
        const int blocks = (int)((total_threads + 255) / 256);
        lightgcn_scatter<<<blocks, 256, 0, stream>>>(
            user_emb, item_emb, edge_norm, u_idx, i_idx, agg_users, agg_items);
        return;
    }

    char* p = (char*)d_ws;
    int*   i_off  = (int*)p;   p += (size_t)(NUM_ITEMS + 1) * sizeof(int);
    int*   u_off  = (int*)p;   p += (size_t)(NUM_USERS + 1) * sizeof(int);
    int*   i_cur  = (int*)p;   p += (size_t)NUM_ITEMS * sizeof(int);
    int*   u_cur  = (int*)p;   p += (size_t)NUM_USERS * sizeof(int);
    p = (char*)(((uintptr_t)p + 63) & ~(uintptr_t)63);
    int*   ci_src = (int*)p;   p += (size_t)NUM_EDGES * sizeof(int);
    float* ci_w   = (float*)p; p += (size_t)NUM_EDGES * sizeof(float);
    int*   cu_src = (int*)p;   p += (size_t)NUM_EDGES * sizeof(int);
    float* cu_w   = (float*)p; p += (size_t)NUM_EDGES * sizeof(float);
    p = (char*)(((uintptr_t)p + 63) & ~(uintptr_t)63);
    ushort* ue16  = (ushort*)p; p += (size_t)NUM_USERS * DIM * sizeof(ushort);
    ushort* ie16  = (ushort*)p;

    const bool use_bf16 = (ws_size >= need_full);

    // zero count arrays (i_off and u_off are contiguous)
    hipMemsetAsync(i_off, 0, (size_t)(NUM_ITEMS + 1 + NUM_USERS + 1) * sizeof(int),
                   stream);

    if (use_bf16) {
        const int un4 = NUM_USERS * DIM / 4;
        const int in4 = NUM_ITEMS * DIM / 4;
        convert_bf16<<<(un4 + 255) / 256, 256, 0, stream>>>(
            (const float4*)user_emb, ue16, un4);
        convert_bf16<<<(in4 + 255) / 256, 256, 0, stream>>>(
            (const float4*)item_emb, ie16, in4);
    }

    edge_hist<<<(NUM_EDGES / 4 + 255) / 256, 256, 0, stream>>>(
        (const int4*)u_idx, (const int4*)i_idx, u_off, i_off);
    scan_offsets<<<2, 1024, 0, stream>>>(i_off, i_cur, u_off, u_cur);
    edge_place<<<(NUM_EDGES + 255) / 256, 256, 0, stream>>>(
        u_idx, i_idx, edge_norm, i_cur, u_cur, ci_src, ci_w, cu_src, cu_w);

    if (use_bf16) {
        gather_rows_bf16<<<((NUM_ITEMS * 64) + 255) / 256, 256, 0, stream>>>(
            i_off, ci_src, ci_w, ue16, agg_items, NUM_ITEMS);
        gather_rows_bf16<<<((NUM_USERS * 64) + 255) / 256, 256, 0, stream>>>(
            u_off, cu_src, cu_w, ie16, agg_users, NUM_USERS);
    } else {
        gather_rows_f32<<<((NUM_ITEMS * 64) + 255) / 256, 256, 0, stream>>>(
            i_off, ci_src, ci_w, user_emb, agg_items, NUM_ITEMS);
        gather_rows_f32<<<((NUM_USERS * 64) + 255) / 256, 256, 0, stream>>>(
            u_off, cu_src, cu_w, item_emb, agg_users, NUM_USERS);
    }
}